// Round 5
// baseline (811.429 us; speedup 1.0000x reference)
//
#include <hip/hip_runtime.h>
#include <hip/hip_bf16.h>
#include <math.h>

#define EPSF 1e-5f
#define SELHI 0x05040100u
#define SELLO 0x07060302u

typedef __attribute__((ext_vector_type(8))) short bf16x8;
typedef __attribute__((ext_vector_type(16))) float f32x16;

// pack float -> u32 { low16 = hi-bf16 (truncated), high16 = lo-bf16 (residual) }
__device__ __forceinline__ uint32_t packsplit(float x) {
  uint32_t xb = __builtin_bit_cast(uint32_t, x);
  float hi = __builtin_bit_cast(float, xb & 0xFFFF0000u);
  float resid = x - hi;
  return __builtin_amdgcn_perm(__builtin_bit_cast(uint32_t, resid), xb, 0x07060302u);
}

// 8 packed u32 -> one 8xbf16 fragment (SELHI = hi halves, SELLO = residuals)
__device__ __forceinline__ uint4 mkfrag8(const uint32_t* p, uint32_t sel) {
  uint4 u;
  u.x = __builtin_amdgcn_perm(p[1], p[0], sel);
  u.y = __builtin_amdgcn_perm(p[3], p[2], sel);
  u.z = __builtin_amdgcn_perm(p[5], p[4], sel);
  u.w = __builtin_amdgcn_perm(p[7], p[6], sel);
  return u;
}

__device__ __forceinline__ f32x16 mf(uint4 a, uint4 b, f32x16 c) {
  return __builtin_amdgcn_mfma_f32_32x32x16_bf16(
      __builtin_bit_cast(bf16x8, a), __builtin_bit_cast(bf16x8, b), c, 0, 0, 0);
}

#define F4C(v, i) ((i) == 0 ? (v).x : (i) == 1 ? (v).y : (i) == 2 ? (v).z : (v).w)

// =====================================================================
// Kernel 1: fused projection GEMM (unchanged)
// =====================================================================
__global__ __launch_bounds__(256) void proj_gemm_kernel(
    const float* __restrict__ x,
    const float* __restrict__ Wk, const float* __restrict__ bk,
    const float* __restrict__ Wv, const float* __restrict__ bv,
    const float* __restrict__ Wq, const float* __restrict__ bq,
    float* __restrict__ proj)
{
  __shared__ float As[16][68];
  __shared__ float Bs[16][68];
  const int col0 = blockIdx.x * 64;
  const int row0 = blockIdx.y * 64;
  const float* Bp; const float* bias; int ldb, bcol, relu;
  if (col0 < 512)       { Bp = Wk; bias = bk; ldb = 512;  bcol = col0;        relu = 1; }
  else if (col0 < 1536) { Bp = Wv; bias = bv; ldb = 1024; bcol = col0 - 512;  relu = 0; }
  else                  { Bp = Wq; bias = bq; ldb = 512;  bcol = col0 - 1536; relu = 1; }
  const int tid = threadIdx.x;
  const int tr = tid >> 4, tc = tid & 15;
  float acc[4][4] = {};
  for (int k0 = 0; k0 < 1024; k0 += 16) {
    {
      int r = tid >> 2, kk = (tid & 3) << 2;
      float4 a4 = *(const float4*)&x[(size_t)(row0 + r) * 1024 + k0 + kk];
      As[kk+0][r] = a4.x; As[kk+1][r] = a4.y; As[kk+2][r] = a4.z; As[kk+3][r] = a4.w;
    }
    {
      int kr = tid >> 4, cc = (tid & 15) << 2;
      *(float4*)&Bs[kr][cc] = *(const float4*)&Bp[(size_t)(k0 + kr) * ldb + bcol + cc];
    }
    __syncthreads();
    #pragma unroll
    for (int k = 0; k < 16; ++k) {
      float4 av4 = *(const float4*)&As[k][tr*4];
      float4 bv4 = *(const float4*)&Bs[k][tc*4];
      float av[4] = {av4.x, av4.y, av4.z, av4.w};
      float bb[4] = {bv4.x, bv4.y, bv4.z, bv4.w};
      #pragma unroll
      for (int i = 0; i < 4; ++i)
        #pragma unroll
        for (int j = 0; j < 4; ++j)
          acc[i][j] = fmaf(av[i], bb[j], acc[i][j]);
    }
    __syncthreads();
  }
  #pragma unroll
  for (int i = 0; i < 4; ++i) {
    int r = row0 + tr*4 + i;
    #pragma unroll
    for (int j = 0; j < 4; ++j) {
      int cl = tc*4 + j;
      float v = acc[i][j] + bias[bcol + cl];
      if (relu) v = fmaxf(v, 0.f);
      proj[(size_t)r * 2048 + col0 + cl] = v;
    }
  }
}

// =====================================================================
// Kernel 2: fused memory kernel, R4.
//   vs R3: (1) LDS 63->50 KB (XOR-swizzled pk, overlaid arenas) for
//   3 blocks/CU; (2) phase-B MFMAs software-pipelined one superstep
//   ahead (independent aBnext chain hides MFMA latency under C/ELEM/D);
//   (3) memories loads issued ~700cy ahead of ELEM use.
// =====================================================================
__global__ __launch_bounds__(256, 3) void fused_mem_kernel(
    const float* __restrict__ memories,   // [512][2048][64]
    const float* __restrict__ addresses,  // [2048][64]
    const float* __restrict__ proj,       // [512][2048] = fk|v|fq
    float* __restrict__ attn)             // [512][512]
{
  // 50 KB arena:
  //  [0,2048)      fkFrag          (epilogue: n2stage/norm2/den2 overlay)
  //  [2048,4096)   vFrag
  //  [4096,4608)   fq (512 floats)
  //  [4608,12800)  pk region (pbuf at start, pk[4 waves] in main, stage in epilogue)
  __shared__ uint32_t SH[12800];

  const int b = blockIdx.x, tid = threadIdx.x;
  const int wave = tid >> 6, lane = tid & 63;
  const int g32 = lane >> 5, c32 = lane & 31;

  uint32_t* fkFrag = SH;
  uint32_t* vFrag  = SH + 2048;
  float*    fqb    = (float*)(SH + 4096);
  uint32_t* pkbase = SH + 4608;
  uint32_t* pF = pkbase + wave * 2048;   // [16][64] u32, col ^= (row&7)<<2
  uint32_t* pN = pF + 1024;

  // ---- stage proj row (pbuf overlays pk region) ----
  float* pbuf = (float*)pkbase;
  {
    const float* prow = proj + (size_t)b * 2048;
    *(float4*)&pbuf[tid*8]   = *(const float4*)&prow[tid*8];
    *(float4*)&pbuf[tid*8+4] = *(const float4*)&prow[tid*8+4];
  }
  __syncthreads();

  // ---- one-time fragment packing (wave w: kstep w, e-tile w) + fq copy ----
  {
    const int ks = wave;
    float4 f0 = *(const float4*)&pbuf[c32*64 + ks*16 + g32*8];
    float4 f1 = *(const float4*)&pbuf[c32*64 + ks*16 + g32*8 + 4];
    uint32_t p[8] = { packsplit(f0.x), packsplit(f0.y), packsplit(f0.z), packsplit(f0.w),
                      packsplit(f1.x), packsplit(f1.y), packsplit(f1.z), packsplit(f1.w) };
    *(uint4*)&fkFrag[((ks*2+0)*64 + lane)*4] = mkfrag8(p, SELHI);
    *(uint4*)&fkFrag[((ks*2+1)*64 + lane)*4] = mkfrag8(p, SELLO);
    const int t = wave;
    uint32_t q[8];
    #pragma unroll
    for (int j = 0; j < 8; ++j) {
      int h = (g32*8 + j) & 7;
      q[j] = packsplit(pbuf[512 + h*128 + t*32 + c32]);
    }
    *(uint4*)&vFrag[((t*2+0)*64 + lane)*4] = mkfrag8(q, SELHI);
    *(uint4*)&vFrag[((t*2+1)*64 + lane)*4] = mkfrag8(q, SELLO);
    *(float2*)&fqb[tid*2] = *(const float2*)&pbuf[1536 + tid*2];
  }
  __syncthreads();

  f32x16 Zv;
  #pragma unroll
  for (int r = 0; r < 16; ++r) Zv[r] = 0.f;
  f32x16 aD00 = Zv, aD01 = Zv, aD10 = Zv, aD11 = Zv;
  float n2a[32];
  #pragma unroll
  for (int k = 0; k < 32; ++k) n2a[k] = 0.f;

  const float* aRow0 = addresses + (size_t)(wave*512 + c32) * 64;
  const float* mRow0 = memories + ((size_t)b*2048 + wave*512 + c32) * 64;

  auto do_mfma = [&]() {
    uint32_t rf0[8], rf1[8], rn0[8], rn1[8];
    #pragma unroll
    for (int e = 0; e < 8; ++e) {
      const int row = g32*8 + e;
      const int cs = c32 ^ ((row & 7) << 2);
      rf0[e] = pF[row*64 + cs];
      rf1[e] = pF[row*64 + 32 + cs];
      rn0[e] = pN[row*64 + cs];
      rn1[e] = pN[row*64 + 32 + cs];
    }
    uint4 A0h = mkfrag8(rf0, SELHI), A0l = mkfrag8(rf0, SELLO);
    uint4 A1h = mkfrag8(rf1, SELHI), A1l = mkfrag8(rf1, SELLO);
    uint4 B0h = mkfrag8(rn0, SELHI), B0l = mkfrag8(rn0, SELLO);
    uint4 B1h = mkfrag8(rn1, SELHI), B1l = mkfrag8(rn1, SELLO);
    aD00 = mf(A0h,B0h,aD00); aD00 = mf(A0h,B0l,aD00); aD00 = mf(A0l,B0h,aD00);
    aD01 = mf(A0h,B1h,aD01); aD01 = mf(A0h,B1l,aD01); aD01 = mf(A0l,B1h,aD01);
    aD10 = mf(A1h,B0h,aD10); aD10 = mf(A1h,B0l,aD10); aD10 = mf(A1l,B0h,aD10);
    aD11 = mf(A1h,B1h,aD11); aD11 = mf(A1h,B1l,aD11); aD11 = mf(A1l,B1h,aD11);
  };

  // qa-pack + issue 12 B-MFMAs for superstep with address row AP into ACC
#define QAPACK_B(AP, ACC) do {                                         \
    _Pragma("unroll")                                                  \
    for (int ks = 0; ks < 4; ++ks) {                                   \
      float4 f0_ = *(const float4*)((AP) + ks*16 + g32*8);             \
      float4 f1_ = *(const float4*)((AP) + ks*16 + g32*8 + 4);         \
      uint32_t qp_[8] = {                                              \
        packsplit(fmaxf(f0_.x,0.f)), packsplit(fmaxf(f0_.y,0.f)),      \
        packsplit(fmaxf(f0_.z,0.f)), packsplit(fmaxf(f0_.w,0.f)),      \
        packsplit(fmaxf(f1_.x,0.f)), packsplit(fmaxf(f1_.y,0.f)),      \
        packsplit(fmaxf(f1_.z,0.f)), packsplit(fmaxf(f1_.w,0.f)) };    \
      uint4 Bh_ = mkfrag8(qp_, SELHI), Bl_ = mkfrag8(qp_, SELLO);      \
      uint4 Ah_ = *(uint4*)&fkFrag[((ks*2+0)*64 + lane)*4];            \
      uint4 Al_ = *(uint4*)&fkFrag[((ks*2+1)*64 + lane)*4];            \
      ACC = mf(Ah_,Bh_,ACC); ACC = mf(Ah_,Bl_,ACC); ACC = mf(Al_,Bh_,ACC); \
    } } while(0)

#define PKHALF                                                              \
    { const int r_ = c32 & 15;                                              \
      uint32_t* bF_ = &pF[r_*64];                                           \
      uint32_t* bN_ = &pN[r_*64];                                           \
      const int sx_ = (r_ & 7) << 2;                                        \
      _Pragma("unroll")                                                     \
      for (int t2 = 0; t2 < 2; ++t2)                                        \
        _Pragma("unroll")                                                   \
        for (int rq = 0; rq < 4; ++rq) {                                    \
          const int col = (32*t2 + 8*rq + 4*g32) ^ sx_;                     \
          *(uint4*)&bF_[col] = make_uint4(oF[t2*16+rq*4+0], oF[t2*16+rq*4+1], \
                                          oF[t2*16+rq*4+2], oF[t2*16+rq*4+3]); \
          *(uint4*)&bN_[col] = make_uint4(oN[t2*16+rq*4+0], oN[t2*16+rq*4+1], \
                                          oN[t2*16+rq*4+2], oN[t2*16+rq*4+3]); \
        } }

  // ---- prologue: B(0) + M(0) ----
  f32x16 aBcur = Zv, aBnext;
  float4 M_[8];
  QAPACK_B(aRow0, aBcur);
  #pragma unroll
  for (int k = 0; k < 8; ++k) M_[k] = *(const float4*)(mRow0 + k*8 + g32*4);

  #pragma unroll 1
  for (int ss = 0; ss < 16; ++ss) {
    asm volatile("" ::: "memory");  // block LICM of loop-invariant LDS reads

    // ---- 1. finish B(ss): S, den, rden, S-fragments ----
    float s0 = aBcur[0], s1 = aBcur[1], s2 = aBcur[2], s3 = aBcur[3];
    float own = (s0 + s1) + (s2 + s3);
    float den = own + __shfl_xor(own, 32) + EPSF;
    float rden = 1.f / den;
    float p0 = __shfl_xor(s0, 32), p1 = __shfl_xor(s1, 32),
          p2 = __shfl_xor(s2, 32), p3 = __shfl_xor(s3, 32);
    float z = (g32 == 0) ? 1.f : 0.f;
    uint32_t sp[8] = { packsplit(s0*z), packsplit(s1*z), packsplit(s2*z), packsplit(s3*z),
                       packsplit(p0*z), packsplit(p1*z), packsplit(p2*z), packsplit(p3*z) };
    uint4 Sh = mkfrag8(sp, SELHI), Sl = mkfrag8(sp, SELLO);

    // ---- 2. issue all C-MFMAs (12) ----
    f32x16 aC0 = Zv, aC1 = Zv, aC2 = Zv, aC3 = Zv;
    {
      uint4 Vh, Vl;
      Vh = *(uint4*)&vFrag[(0*64 + lane)*4]; Vl = *(uint4*)&vFrag[(1*64 + lane)*4];
      aC0 = mf(Vh, Sh, aC0); aC0 = mf(Vh, Sl, aC0); aC0 = mf(Vl, Sh, aC0);
      Vh = *(uint4*)&vFrag[(2*64 + lane)*4]; Vl = *(uint4*)&vFrag[(3*64 + lane)*4];
      aC1 = mf(Vh, Sh, aC1); aC1 = mf(Vh, Sl, aC1); aC1 = mf(Vl, Sh, aC1);
      Vh = *(uint4*)&vFrag[(4*64 + lane)*4]; Vl = *(uint4*)&vFrag[(5*64 + lane)*4];
      aC2 = mf(Vh, Sh, aC2); aC2 = mf(Vh, Sl, aC2); aC2 = mf(Vl, Sh, aC2);
      Vh = *(uint4*)&vFrag[(6*64 + lane)*4]; Vl = *(uint4*)&vFrag[(7*64 + lane)*4];
      aC3 = mf(Vh, Sh, aC3); aC3 = mf(Vh, Sl, aC3); aC3 = mf(Vl, Sh, aC3);
    }

    // ---- 3. pipeline: qa-pack + B-MFMAs for ss+1 (independent chain) ----
    aBnext = Zv;
    if (ss < 15) {
      const float* apn = aRow0 + (size_t)(ss+1) * 2048;
      QAPACK_B(apn, aBnext);
    }

    // ---- 4. elementwise (E loads lazy; cache-hot lines) ----
    const float* ap0 = aRow0 + (size_t)ss * 2048;
    float4 E_[4][2];
    uint32_t oF[32], oN[32];
#define ELEM(T2)                                                      \
    _Pragma("unroll")                                                 \
    for (int r = 0; r < 16; ++r) {                                    \
      float upd = ((T2) ? aC1 : aC0)[r] * rden;                       \
      float wx  = ((T2) ? aC3 : aC2)[r] * rden;                       \
      float wp  = 1.f / (1.f + __expf(-wx));                          \
      float mv  = F4C(M_[(T2)*4 + (r>>2)], r & 3);                    \
      float av  = F4C(E_[2*(T2) + (r>>3)][(r>>2) & 1], r & 3);        \
      float nm  = fmaf(wp, upd - mv, mv);                             \
      float fv  = fmaxf(nm + av, 0.f);                                \
      n2a[(T2)*16 + r] += fv;                                         \
      oN[(T2)*16 + r] = packsplit(nm);                                \
      oF[(T2)*16 + r] = packsplit(fv);                                \
    }
    E_[0][0] = *(const float4*)(ap0 + g32*4);
    E_[0][1] = *(const float4*)(ap0 + g32*4 + 8);
    E_[1][0] = *(const float4*)(ap0 + 16 + g32*4);
    E_[1][1] = *(const float4*)(ap0 + 16 + g32*4 + 8);
    ELEM(0)
    E_[2][0] = *(const float4*)(ap0 + 32 + g32*4);
    E_[2][1] = *(const float4*)(ap0 + 32 + g32*4 + 8);
    E_[3][0] = *(const float4*)(ap0 + 48 + g32*4);
    E_[3][1] = *(const float4*)(ap0 + 48 + g32*4 + 8);
    ELEM(1)
#undef ELEM

    // ---- 5. prefetch memories(ss+1) (consumed next body, ~700cy ahead) ----
    if (ss < 15) {
      const float* mp = mRow0 + (size_t)(ss+1) * 2048;
      #pragma unroll
      for (int k = 0; k < 8; ++k) M_[k] = *(const float4*)(mp + k*8 + g32*4);
    }

    // ---- 6. phase D: two 16-row chunks, time-multiplexed pk ----
    if (c32 < 16) PKHALF
    asm volatile("" ::: "memory");
    do_mfma();
    asm volatile("" ::: "memory");
    if (c32 >= 16) PKHALF
    asm volatile("" ::: "memory");
    do_mfma();

    aBcur = aBnext;
  }

  // ================= epilogue =================
  __syncthreads();   // everyone done with fkFrag/vFrag/pk

  float* n2stageF = (float*)SH;            // [4][64]
  float* norm2F   = ((float*)SH) + 256;    // [64]
  float* den2F    = ((float*)SH) + 320;    // [8]
  float* stageF   = (float*)pkbase;        // [4][16][66]

  #pragma unroll
  for (int k = 0; k < 32; ++k) {
    float v = n2a[k];
    v += __shfl_xor(v, 1); v += __shfl_xor(v, 2); v += __shfl_xor(v, 4);
    v += __shfl_xor(v, 8); v += __shfl_xor(v, 16);
    n2a[k] = v;
  }
  if (c32 == 0) {
    #pragma unroll
    for (int t2 = 0; t2 < 2; ++t2)
      #pragma unroll
      for (int r = 0; r < 16; ++r) {
        const int j = 32*t2 + 8*(r>>2) + (r&3) + 4*g32;
        n2stageF[wave*64 + j] = n2a[t2*16 + r];
      }
  }
  __syncthreads();
  if (tid < 64)
    norm2F[tid] = (n2stageF[tid] + n2stageF[64+tid]) + (n2stageF[128+tid] + n2stageF[192+tid]);
  __syncthreads();
  if (tid < 8) {
    float s = 0.f;
    for (int d = 0; d < 64; ++d) s = fmaf(fqb[tid*64 + d], norm2F[d], s);
    den2F[tid] = s + EPSF;
  }

  const int hh = tid >> 5;
  const int ee = (tid & 31) * 2;
  float num2a = 0.f, num2b = 0.f;
  #pragma unroll
  for (int p = 0; p < 4; ++p) {
    const int ti = p >> 1, rh = p & 1;
    #pragma unroll
    for (int q = 0; q < 8; ++q) {
      const int rr = (q & 3) + 8*((q >> 2) & 1) + 4*g32;
      const int r = rh*8 + q;
      float v0 = (ti == 0) ? aD00[r] : aD10[r];
      float v1 = (ti == 0) ? aD01[r] : aD11[r];
      stageF[wave*1056 + rr*66 + c32]      = v0;
      stageF[wave*1056 + rr*66 + 32 + c32] = v1;
    }
    __syncthreads();
    #pragma unroll 8
    for (int dl = 0; dl < 16; ++dl) {
      float2 q0 = *(const float2*)&stageF[0*1056 + dl*66 + ee];
      float2 q1 = *(const float2*)&stageF[1*1056 + dl*66 + ee];
      float2 q2 = *(const float2*)&stageF[2*1056 + dl*66 + ee];
      float2 q3 = *(const float2*)&stageF[3*1056 + dl*66 + ee];
      float v0 = (q0.x + q1.x) + (q2.x + q3.x);
      float v1 = (q0.y + q1.y) + (q2.y + q3.y);
      float fv = fqb[hh*64 + p*16 + dl];
      num2a = fmaf(fv, v0, num2a);
      num2b = fmaf(fv, v1, num2b);
    }
    __syncthreads();
  }
  float rd2 = 1.f / den2F[hh];
  attn[(size_t)b*512 + hh*64 + ee]     = num2a * rd2;
  attn[(size_t)b*512 + hh*64 + ee + 1] = num2b * rd2;
#undef PKHALF
#undef QAPACK_B
}

// =====================================================================
// Kernel 3: out = attn(512x512) @ Wm(512x1024) + bm (unchanged)
// =====================================================================
__global__ __launch_bounds__(256) void out_gemm_kernel(
    const float* __restrict__ A, const float* __restrict__ Wm,
    const float* __restrict__ bm, float* __restrict__ out)
{
  __shared__ float As[16][68];
  __shared__ float Bs[16][68];
  const int col0 = blockIdx.x * 64;
  const int row0 = blockIdx.y * 64;
  const int tid = threadIdx.x;
  const int tr = tid >> 4, tc = tid & 15;
  float acc[4][4] = {};
  for (int k0 = 0; k0 < 512; k0 += 16) {
    {
      int r = tid >> 2, kk = (tid & 3) << 2;
      float4 a4 = *(const float4*)&A[(size_t)(row0 + r) * 512 + k0 + kk];
      As[kk+0][r] = a4.x; As[kk+1][r] = a4.y; As[kk+2][r] = a4.z; As[kk+3][r] = a4.w;
    }
    {
      int kr = tid >> 4, cc = (tid & 15) << 2;
      *(float4*)&Bs[kr][cc] = *(const float4*)&Wm[(size_t)(k0 + kr) * 1024 + col0 + cc];
    }
    __syncthreads();
    #pragma unroll
    for (int k = 0; k < 16; ++k) {
      float4 av4 = *(const float4*)&As[k][tr*4];
      float4 bv4 = *(const float4*)&Bs[k][tc*4];
      float av[4] = {av4.x, av4.y, av4.z, av4.w};
      float bb[4] = {bv4.x, bv4.y, bv4.z, bv4.w};
      #pragma unroll
      for (int i = 0; i < 4; ++i)
        #pragma unroll
        for (int j = 0; j < 4; ++j)
          acc[i][j] = fmaf(av[i], bb[j], acc[i][j]);
    }
    __syncthreads();
  }
  #pragma unroll
  for (int i = 0; i < 4; ++i) {
    int r = row0 + tr*4 + i;
    #pragma unroll
    for (int j = 0; j < 4; ++j) {
      int c = col0 + tc*4 + j;
      out[(size_t)r * 1024 + c] = acc[i][j] + bm[c];
    }
  }
}

extern "C" void kernel_launch(void* const* d_in, const int* in_sizes, int n_in,
                              void* d_out, int out_size, void* d_ws, size_t ws_size,
                              hipStream_t stream)
{
  const float* x    = (const float*)d_in[0];
  const float* mem  = (const float*)d_in[1];
  const float* addr = (const float*)d_in[2];
  const float* Wk   = (const float*)d_in[3];
  const float* bk   = (const float*)d_in[4];
  const float* Wv   = (const float*)d_in[5];
  const float* bv   = (const float*)d_in[6];
  const float* Wq   = (const float*)d_in[7];
  const float* bq   = (const float*)d_in[8];
  const float* Wm   = (const float*)d_in[9];
  const float* bm   = (const float*)d_in[10];
  float* out  = (float*)d_out;
  float* ws   = (float*)d_ws;
  float* proj = ws;                        // 512*2048 floats (4 MB)
  float* attn = ws + (size_t)512 * 2048;   // 512*512 floats (1 MB)

  hipLaunchKernelGGL(proj_gemm_kernel, dim3(32, 8), dim3(256), 0, stream,
                     x, Wk, bk, Wv, bv, Wq, bq, proj);
  hipLaunchKernelGGL(fused_mem_kernel, dim3(512), dim3(256), 0, stream,
                     mem, addr, proj, attn);
  hipLaunchKernelGGL(out_gemm_kernel, dim3(16, 8), dim3(256), 0, stream,
                     attn, Wm, bm, out);
}

// Round 6
// 435.716 us; speedup vs baseline: 1.8623x; 1.8623x over previous
//
#include <hip/hip_runtime.h>
#include <hip/hip_bf16.h>
#include <math.h>

#define EPSF 1e-5f
#define SELHI 0x05040100u
#define SELLO 0x07060302u

typedef __attribute__((ext_vector_type(8))) short bf16x8;
typedef __attribute__((ext_vector_type(16))) float f32x16;

// pack float -> u32 { low16 = hi-bf16 (truncated), high16 = lo-bf16 (residual) }
__device__ __forceinline__ uint32_t packsplit(float x) {
  uint32_t xb = __builtin_bit_cast(uint32_t, x);
  float hi = __builtin_bit_cast(float, xb & 0xFFFF0000u);
  float resid = x - hi;
  return __builtin_amdgcn_perm(__builtin_bit_cast(uint32_t, resid), xb, 0x07060302u);
}

// 8 packed u32 -> one 8xbf16 fragment (SELHI = hi halves, SELLO = residuals)
__device__ __forceinline__ uint4 mkfrag8(const uint32_t* p, uint32_t sel) {
  uint4 u;
  u.x = __builtin_amdgcn_perm(p[1], p[0], sel);
  u.y = __builtin_amdgcn_perm(p[3], p[2], sel);
  u.z = __builtin_amdgcn_perm(p[5], p[4], sel);
  u.w = __builtin_amdgcn_perm(p[7], p[6], sel);
  return u;
}

__device__ __forceinline__ f32x16 mf(uint4 a, uint4 b, f32x16 c) {
  return __builtin_amdgcn_mfma_f32_32x32x16_bf16(
      __builtin_bit_cast(bf16x8, a), __builtin_bit_cast(bf16x8, b), c, 0, 0, 0);
}

#define F4C(v, i) ((i) == 0 ? (v).x : (i) == 1 ? (v).y : (i) == 2 ? (v).z : (v).w)

// =====================================================================
// Kernel 1: fused projection GEMM (unchanged)
// =====================================================================
__global__ __launch_bounds__(256) void proj_gemm_kernel(
    const float* __restrict__ x,
    const float* __restrict__ Wk, const float* __restrict__ bk,
    const float* __restrict__ Wv, const float* __restrict__ bv,
    const float* __restrict__ Wq, const float* __restrict__ bq,
    float* __restrict__ proj)
{
  __shared__ float As[16][68];
  __shared__ float Bs[16][68];
  const int col0 = blockIdx.x * 64;
  const int row0 = blockIdx.y * 64;
  const float* Bp; const float* bias; int ldb, bcol, relu;
  if (col0 < 512)       { Bp = Wk; bias = bk; ldb = 512;  bcol = col0;        relu = 1; }
  else if (col0 < 1536) { Bp = Wv; bias = bv; ldb = 1024; bcol = col0 - 512;  relu = 0; }
  else                  { Bp = Wq; bias = bq; ldb = 512;  bcol = col0 - 1536; relu = 1; }
  const int tid = threadIdx.x;
  const int tr = tid >> 4, tc = tid & 15;
  float acc[4][4] = {};
  for (int k0 = 0; k0 < 1024; k0 += 16) {
    {
      int r = tid >> 2, kk = (tid & 3) << 2;
      float4 a4 = *(const float4*)&x[(size_t)(row0 + r) * 1024 + k0 + kk];
      As[kk+0][r] = a4.x; As[kk+1][r] = a4.y; As[kk+2][r] = a4.z; As[kk+3][r] = a4.w;
    }
    {
      int kr = tid >> 4, cc = (tid & 15) << 2;
      *(float4*)&Bs[kr][cc] = *(const float4*)&Bp[(size_t)(k0 + kr) * ldb + bcol + cc];
    }
    __syncthreads();
    #pragma unroll
    for (int k = 0; k < 16; ++k) {
      float4 av4 = *(const float4*)&As[k][tr*4];
      float4 bv4 = *(const float4*)&Bs[k][tc*4];
      float av[4] = {av4.x, av4.y, av4.z, av4.w};
      float bb[4] = {bv4.x, bv4.y, bv4.z, bv4.w};
      #pragma unroll
      for (int i = 0; i < 4; ++i)
        #pragma unroll
        for (int j = 0; j < 4; ++j)
          acc[i][j] = fmaf(av[i], bb[j], acc[i][j]);
    }
    __syncthreads();
  }
  #pragma unroll
  for (int i = 0; i < 4; ++i) {
    int r = row0 + tr*4 + i;
    #pragma unroll
    for (int j = 0; j < 4; ++j) {
      int cl = tc*4 + j;
      float v = acc[i][j] + bias[bcol + cl];
      if (relu) v = fmaxf(v, 0.f);
      proj[(size_t)r * 2048 + col0 + cl] = v;
    }
  }
}

// =====================================================================
// Kernel 2: fused memory kernel, R5.
//   = R4 structure (pipelined phase-B MFMA chain, memories prefetch,
//   XOR-swizzled pk, overlaid 50 KB LDS arena) but with
//   __launch_bounds__(256,2): R4's (256,3) capped VGPRs at ~170 vs a
//   ~210 live set -> massive scratch spill (VGPR 84, 2.4 GB/dispatch
//   scratch traffic). 2 waves/EU allows 256 VGPRs; no spill.
// =====================================================================
__global__ __launch_bounds__(256, 2) void fused_mem_kernel(
    const float* __restrict__ memories,   // [512][2048][64]
    const float* __restrict__ addresses,  // [2048][64]
    const float* __restrict__ proj,       // [512][2048] = fk|v|fq
    float* __restrict__ attn)             // [512][512]
{
  // 50 KB arena:
  //  [0,2048)      fkFrag          (epilogue: n2stage/norm2/den2 overlay)
  //  [2048,4096)   vFrag
  //  [4096,4608)   fq (512 floats)
  //  [4608,12800)  pk region (pbuf at start, pk[4 waves] in main, stage in epilogue)
  __shared__ uint32_t SH[12800];

  const int b = blockIdx.x, tid = threadIdx.x;
  const int wave = tid >> 6, lane = tid & 63;
  const int g32 = lane >> 5, c32 = lane & 31;

  uint32_t* fkFrag = SH;
  uint32_t* vFrag  = SH + 2048;
  float*    fqb    = (float*)(SH + 4096);
  uint32_t* pkbase = SH + 4608;
  uint32_t* pF = pkbase + wave * 2048;   // [16][64] u32, col ^= (row&7)<<2
  uint32_t* pN = pF + 1024;

  // ---- stage proj row (pbuf overlays pk region) ----
  float* pbuf = (float*)pkbase;
  {
    const float* prow = proj + (size_t)b * 2048;
    *(float4*)&pbuf[tid*8]   = *(const float4*)&prow[tid*8];
    *(float4*)&pbuf[tid*8+4] = *(const float4*)&prow[tid*8+4];
  }
  __syncthreads();

  // ---- one-time fragment packing (wave w: kstep w, e-tile w) + fq copy ----
  {
    const int ks = wave;
    float4 f0 = *(const float4*)&pbuf[c32*64 + ks*16 + g32*8];
    float4 f1 = *(const float4*)&pbuf[c32*64 + ks*16 + g32*8 + 4];
    uint32_t p[8] = { packsplit(f0.x), packsplit(f0.y), packsplit(f0.z), packsplit(f0.w),
                      packsplit(f1.x), packsplit(f1.y), packsplit(f1.z), packsplit(f1.w) };
    *(uint4*)&fkFrag[((ks*2+0)*64 + lane)*4] = mkfrag8(p, SELHI);
    *(uint4*)&fkFrag[((ks*2+1)*64 + lane)*4] = mkfrag8(p, SELLO);
    const int t = wave;
    uint32_t q[8];
    #pragma unroll
    for (int j = 0; j < 8; ++j) {
      int h = (g32*8 + j) & 7;
      q[j] = packsplit(pbuf[512 + h*128 + t*32 + c32]);
    }
    *(uint4*)&vFrag[((t*2+0)*64 + lane)*4] = mkfrag8(q, SELHI);
    *(uint4*)&vFrag[((t*2+1)*64 + lane)*4] = mkfrag8(q, SELLO);
    *(float2*)&fqb[tid*2] = *(const float2*)&pbuf[1536 + tid*2];
  }
  __syncthreads();

  f32x16 Zv;
  #pragma unroll
  for (int r = 0; r < 16; ++r) Zv[r] = 0.f;
  f32x16 aD00 = Zv, aD01 = Zv, aD10 = Zv, aD11 = Zv;
  float n2a[32];
  #pragma unroll
  for (int k = 0; k < 32; ++k) n2a[k] = 0.f;

  const float* aRow0 = addresses + (size_t)(wave*512 + c32) * 64;
  const float* mRow0 = memories + ((size_t)b*2048 + wave*512 + c32) * 64;

  auto do_mfma = [&]() {
    uint32_t rf0[8], rf1[8], rn0[8], rn1[8];
    #pragma unroll
    for (int e = 0; e < 8; ++e) {
      const int row = g32*8 + e;
      const int cs = c32 ^ ((row & 7) << 2);
      rf0[e] = pF[row*64 + cs];
      rf1[e] = pF[row*64 + 32 + cs];
      rn0[e] = pN[row*64 + cs];
      rn1[e] = pN[row*64 + 32 + cs];
    }
    uint4 A0h = mkfrag8(rf0, SELHI), A0l = mkfrag8(rf0, SELLO);
    uint4 A1h = mkfrag8(rf1, SELHI), A1l = mkfrag8(rf1, SELLO);
    uint4 B0h = mkfrag8(rn0, SELHI), B0l = mkfrag8(rn0, SELLO);
    uint4 B1h = mkfrag8(rn1, SELHI), B1l = mkfrag8(rn1, SELLO);
    aD00 = mf(A0h,B0h,aD00); aD00 = mf(A0h,B0l,aD00); aD00 = mf(A0l,B0h,aD00);
    aD01 = mf(A0h,B1h,aD01); aD01 = mf(A0h,B1l,aD01); aD01 = mf(A0l,B1h,aD01);
    aD10 = mf(A1h,B0h,aD10); aD10 = mf(A1h,B0l,aD10); aD10 = mf(A1l,B0h,aD10);
    aD11 = mf(A1h,B1h,aD11); aD11 = mf(A1h,B1l,aD11); aD11 = mf(A1l,B1h,aD11);
  };

  // qa-pack + issue 12 B-MFMAs for superstep with address row AP into ACC
#define QAPACK_B(AP, ACC) do {                                         \
    _Pragma("unroll")                                                  \
    for (int ks = 0; ks < 4; ++ks) {                                   \
      float4 f0_ = *(const float4*)((AP) + ks*16 + g32*8);             \
      float4 f1_ = *(const float4*)((AP) + ks*16 + g32*8 + 4);         \
      uint32_t qp_[8] = {                                              \
        packsplit(fmaxf(f0_.x,0.f)), packsplit(fmaxf(f0_.y,0.f)),      \
        packsplit(fmaxf(f0_.z,0.f)), packsplit(fmaxf(f0_.w,0.f)),      \
        packsplit(fmaxf(f1_.x,0.f)), packsplit(fmaxf(f1_.y,0.f)),      \
        packsplit(fmaxf(f1_.z,0.f)), packsplit(fmaxf(f1_.w,0.f)) };    \
      uint4 Bh_ = mkfrag8(qp_, SELHI), Bl_ = mkfrag8(qp_, SELLO);      \
      uint4 Ah_ = *(uint4*)&fkFrag[((ks*2+0)*64 + lane)*4];            \
      uint4 Al_ = *(uint4*)&fkFrag[((ks*2+1)*64 + lane)*4];            \
      ACC = mf(Ah_,Bh_,ACC); ACC = mf(Ah_,Bl_,ACC); ACC = mf(Al_,Bh_,ACC); \
    } } while(0)

#define PKHALF                                                              \
    { const int r_ = c32 & 15;                                              \
      uint32_t* bF_ = &pF[r_*64];                                           \
      uint32_t* bN_ = &pN[r_*64];                                           \
      const int sx_ = (r_ & 7) << 2;                                        \
      _Pragma("unroll")                                                     \
      for (int t2 = 0; t2 < 2; ++t2)                                        \
        _Pragma("unroll")                                                   \
        for (int rq = 0; rq < 4; ++rq) {                                    \
          const int col = (32*t2 + 8*rq + 4*g32) ^ sx_;                     \
          *(uint4*)&bF_[col] = make_uint4(oF[t2*16+rq*4+0], oF[t2*16+rq*4+1], \
                                          oF[t2*16+rq*4+2], oF[t2*16+rq*4+3]); \
          *(uint4*)&bN_[col] = make_uint4(oN[t2*16+rq*4+0], oN[t2*16+rq*4+1], \
                                          oN[t2*16+rq*4+2], oN[t2*16+rq*4+3]); \
        } }

  // ---- prologue: B(0) + M(0) ----
  f32x16 aBcur = Zv, aBnext;
  float4 M_[8];
  QAPACK_B(aRow0, aBcur);
  #pragma unroll
  for (int k = 0; k < 8; ++k) M_[k] = *(const float4*)(mRow0 + k*8 + g32*4);

  #pragma unroll 1
  for (int ss = 0; ss < 16; ++ss) {
    asm volatile("" ::: "memory");  // block LICM of loop-invariant LDS reads

    // ---- 1. finish B(ss): S, den, rden, S-fragments ----
    float s0 = aBcur[0], s1 = aBcur[1], s2 = aBcur[2], s3 = aBcur[3];
    float own = (s0 + s1) + (s2 + s3);
    float den = own + __shfl_xor(own, 32) + EPSF;
    float rden = 1.f / den;
    float p0 = __shfl_xor(s0, 32), p1 = __shfl_xor(s1, 32),
          p2 = __shfl_xor(s2, 32), p3 = __shfl_xor(s3, 32);
    float z = (g32 == 0) ? 1.f : 0.f;
    uint32_t sp[8] = { packsplit(s0*z), packsplit(s1*z), packsplit(s2*z), packsplit(s3*z),
                       packsplit(p0*z), packsplit(p1*z), packsplit(p2*z), packsplit(p3*z) };
    uint4 Sh = mkfrag8(sp, SELHI), Sl = mkfrag8(sp, SELLO);

    // ---- 2. issue all C-MFMAs (12) ----
    f32x16 aC0 = Zv, aC1 = Zv, aC2 = Zv, aC3 = Zv;
    {
      uint4 Vh, Vl;
      Vh = *(uint4*)&vFrag[(0*64 + lane)*4]; Vl = *(uint4*)&vFrag[(1*64 + lane)*4];
      aC0 = mf(Vh, Sh, aC0); aC0 = mf(Vh, Sl, aC0); aC0 = mf(Vl, Sh, aC0);
      Vh = *(uint4*)&vFrag[(2*64 + lane)*4]; Vl = *(uint4*)&vFrag[(3*64 + lane)*4];
      aC1 = mf(Vh, Sh, aC1); aC1 = mf(Vh, Sl, aC1); aC1 = mf(Vl, Sh, aC1);
      Vh = *(uint4*)&vFrag[(4*64 + lane)*4]; Vl = *(uint4*)&vFrag[(5*64 + lane)*4];
      aC2 = mf(Vh, Sh, aC2); aC2 = mf(Vh, Sl, aC2); aC2 = mf(Vl, Sh, aC2);
      Vh = *(uint4*)&vFrag[(6*64 + lane)*4]; Vl = *(uint4*)&vFrag[(7*64 + lane)*4];
      aC3 = mf(Vh, Sh, aC3); aC3 = mf(Vh, Sl, aC3); aC3 = mf(Vl, Sh, aC3);
    }

    // ---- 3. pipeline: qa-pack + B-MFMAs for ss+1 (independent chain) ----
    aBnext = Zv;
    if (ss < 15) {
      const float* apn = aRow0 + (size_t)(ss+1) * 2048;
      QAPACK_B(apn, aBnext);
    }

    // ---- 4. elementwise (E loads lazy; cache-hot lines) ----
    const float* ap0 = aRow0 + (size_t)ss * 2048;
    float4 E_[4][2];
    uint32_t oF[32], oN[32];
#define ELEM(T2)                                                      \
    _Pragma("unroll")                                                 \
    for (int r = 0; r < 16; ++r) {                                    \
      float upd = ((T2) ? aC1 : aC0)[r] * rden;                       \
      float wx  = ((T2) ? aC3 : aC2)[r] * rden;                       \
      float wp  = 1.f / (1.f + __expf(-wx));                          \
      float mv  = F4C(M_[(T2)*4 + (r>>2)], r & 3);                    \
      float av  = F4C(E_[2*(T2) + (r>>3)][(r>>2) & 1], r & 3);        \
      float nm  = fmaf(wp, upd - mv, mv);                             \
      float fv  = fmaxf(nm + av, 0.f);                                \
      n2a[(T2)*16 + r] += fv;                                         \
      oN[(T2)*16 + r] = packsplit(nm);                                \
      oF[(T2)*16 + r] = packsplit(fv);                                \
    }
    E_[0][0] = *(const float4*)(ap0 + g32*4);
    E_[0][1] = *(const float4*)(ap0 + g32*4 + 8);
    E_[1][0] = *(const float4*)(ap0 + 16 + g32*4);
    E_[1][1] = *(const float4*)(ap0 + 16 + g32*4 + 8);
    ELEM(0)
    E_[2][0] = *(const float4*)(ap0 + 32 + g32*4);
    E_[2][1] = *(const float4*)(ap0 + 32 + g32*4 + 8);
    E_[3][0] = *(const float4*)(ap0 + 48 + g32*4);
    E_[3][1] = *(const float4*)(ap0 + 48 + g32*4 + 8);
    ELEM(1)
#undef ELEM

    // ---- 5. prefetch memories(ss+1) (consumed next body, ~700cy ahead) ----
    if (ss < 15) {
      const float* mp = mRow0 + (size_t)(ss+1) * 2048;
      #pragma unroll
      for (int k = 0; k < 8; ++k) M_[k] = *(const float4*)(mp + k*8 + g32*4);
    }

    // ---- 6. phase D: two 16-row chunks, time-multiplexed pk ----
    if (c32 < 16) PKHALF
    asm volatile("" ::: "memory");
    do_mfma();
    asm volatile("" ::: "memory");
    if (c32 >= 16) PKHALF
    asm volatile("" ::: "memory");
    do_mfma();

    aBcur = aBnext;
  }

  // ================= epilogue =================
  __syncthreads();   // everyone done with fkFrag/vFrag/pk

  float* n2stageF = (float*)SH;            // [4][64]
  float* norm2F   = ((float*)SH) + 256;    // [64]
  float* den2F    = ((float*)SH) + 320;    // [8]
  float* stageF   = (float*)pkbase;        // [4][16][66]

  #pragma unroll
  for (int k = 0; k < 32; ++k) {
    float v = n2a[k];
    v += __shfl_xor(v, 1); v += __shfl_xor(v, 2); v += __shfl_xor(v, 4);
    v += __shfl_xor(v, 8); v += __shfl_xor(v, 16);
    n2a[k] = v;
  }
  if (c32 == 0) {
    #pragma unroll
    for (int t2 = 0; t2 < 2; ++t2)
      #pragma unroll
      for (int r = 0; r < 16; ++r) {
        const int j = 32*t2 + 8*(r>>2) + (r&3) + 4*g32;
        n2stageF[wave*64 + j] = n2a[t2*16 + r];
      }
  }
  __syncthreads();
  if (tid < 64)
    norm2F[tid] = (n2stageF[tid] + n2stageF[64+tid]) + (n2stageF[128+tid] + n2stageF[192+tid]);
  __syncthreads();
  if (tid < 8) {
    float s = 0.f;
    for (int d = 0; d < 64; ++d) s = fmaf(fqb[tid*64 + d], norm2F[d], s);
    den2F[tid] = s + EPSF;
  }

  const int hh = tid >> 5;
  const int ee = (tid & 31) * 2;
  float num2a = 0.f, num2b = 0.f;
  #pragma unroll
  for (int p = 0; p < 4; ++p) {
    const int ti = p >> 1, rh = p & 1;
    #pragma unroll
    for (int q = 0; q < 8; ++q) {
      const int rr = (q & 3) + 8*((q >> 2) & 1) + 4*g32;
      const int r = rh*8 + q;
      float v0 = (ti == 0) ? aD00[r] : aD10[r];
      float v1 = (ti == 0) ? aD01[r] : aD11[r];
      stageF[wave*1056 + rr*66 + c32]      = v0;
      stageF[wave*1056 + rr*66 + 32 + c32] = v1;
    }
    __syncthreads();
    #pragma unroll 8
    for (int dl = 0; dl < 16; ++dl) {
      float2 q0 = *(const float2*)&stageF[0*1056 + dl*66 + ee];
      float2 q1 = *(const float2*)&stageF[1*1056 + dl*66 + ee];
      float2 q2 = *(const float2*)&stageF[2*1056 + dl*66 + ee];
      float2 q3 = *(const float2*)&stageF[3*1056 + dl*66 + ee];
      float v0 = (q0.x + q1.x) + (q2.x + q3.x);
      float v1 = (q0.y + q1.y) + (q2.y + q3.y);
      float fv = fqb[hh*64 + p*16 + dl];
      num2a = fmaf(fv, v0, num2a);
      num2b = fmaf(fv, v1, num2b);
    }
    __syncthreads();
  }
  float rd2 = 1.f / den2F[hh];
  attn[(size_t)b*512 + hh*64 + ee]     = num2a * rd2;
  attn[(size_t)b*512 + hh*64 + ee + 1] = num2b * rd2;
#undef PKHALF
#undef QAPACK_B
}

// =====================================================================
// Kernel 3: out = attn(512x512) @ Wm(512x1024) + bm (unchanged)
// =====================================================================
__global__ __launch_bounds__(256) void out_gemm_kernel(
    const float* __restrict__ A, const float* __restrict__ Wm,
    const float* __restrict__ bm, float* __restrict__ out)
{
  __shared__ float As[16][68];
  __shared__ float Bs[16][68];
  const int col0 = blockIdx.x * 64;
  const int row0 = blockIdx.y * 64;
  const int tid = threadIdx.x;
  const int tr = tid >> 4, tc = tid & 15;
  float acc[4][4] = {};
  for (int k0 = 0; k0 < 512; k0 += 16) {
    {
      int r = tid >> 2, kk = (tid & 3) << 2;
      float4 a4 = *(const float4*)&A[(size_t)(row0 + r) * 512 + k0 + kk];
      As[kk+0][r] = a4.x; As[kk+1][r] = a4.y; As[kk+2][r] = a4.z; As[kk+3][r] = a4.w;
    }
    {
      int kr = tid >> 4, cc = (tid & 15) << 2;
      *(float4*)&Bs[kr][cc] = *(const float4*)&Wm[(size_t)(k0 + kr) * 1024 + col0 + cc];
    }
    __syncthreads();
    #pragma unroll
    for (int k = 0; k < 16; ++k) {
      float4 av4 = *(const float4*)&As[k][tr*4];
      float4 bv4 = *(const float4*)&Bs[k][tc*4];
      float av[4] = {av4.x, av4.y, av4.z, av4.w};
      float bb[4] = {bv4.x, bv4.y, bv4.z, bv4.w};
      #pragma unroll
      for (int i = 0; i < 4; ++i)
        #pragma unroll
        for (int j = 0; j < 4; ++j)
          acc[i][j] = fmaf(av[i], bb[j], acc[i][j]);
    }
    __syncthreads();
  }
  #pragma unroll
  for (int i = 0; i < 4; ++i) {
    int r = row0 + tr*4 + i;
    #pragma unroll
    for (int j = 0; j < 4; ++j) {
      int c = col0 + tc*4 + j;
      out[(size_t)r * 1024 + c] = acc[i][j] + bm[c];
    }
  }
}

extern "C" void kernel_launch(void* const* d_in, const int* in_sizes, int n_in,
                              void* d_out, int out_size, void* d_ws, size_t ws_size,
                              hipStream_t stream)
{
  const float* x    = (const float*)d_in[0];
  const float* mem  = (const float*)d_in[1];
  const float* addr = (const float*)d_in[2];
  const float* Wk   = (const float*)d_in[3];
  const float* bk   = (const float*)d_in[4];
  const float* Wv   = (const float*)d_in[5];
  const float* bv   = (const float*)d_in[6];
  const float* Wq   = (const float*)d_in[7];
  const float* bq   = (const float*)d_in[8];
  const float* Wm   = (const float*)d_in[9];
  const float* bm   = (const float*)d_in[10];
  float* out  = (float*)d_out;
  float* ws   = (float*)d_ws;
  float* proj = ws;                        // 512*2048 floats (4 MB)
  float* attn = ws + (size_t)512 * 2048;   // 512*512 floats (1 MB)

  hipLaunchKernelGGL(proj_gemm_kernel, dim3(32, 8), dim3(256), 0, stream,
                     x, Wk, bk, Wv, bv, Wq, bq, proj);
  hipLaunchKernelGGL(fused_mem_kernel, dim3(512), dim3(256), 0, stream,
                     mem, addr, proj, attn);
  hipLaunchKernelGGL(out_gemm_kernel, dim3(16, 8), dim3(256), 0, stream,
                     attn, Wm, bm, out);
}

// Round 7
// 235.314 us; speedup vs baseline: 3.4483x; 1.8516x over previous
//
#include <hip/hip_runtime.h>
#include <hip/hip_bf16.h>
#include <math.h>

#define EPSF 1e-5f
#define SELHI 0x05040100u
#define SELLO 0x07060302u

typedef __attribute__((ext_vector_type(8))) short bf16x8;
typedef __attribute__((ext_vector_type(16))) float f32x16;

// pack float -> u32 { low16 = hi-bf16 (truncated), high16 = lo-bf16 (residual) }
__device__ __forceinline__ uint32_t packsplit(float x) {
  uint32_t xb = __builtin_bit_cast(uint32_t, x);
  float hi = __builtin_bit_cast(float, xb & 0xFFFF0000u);
  float resid = x - hi;
  return __builtin_amdgcn_perm(__builtin_bit_cast(uint32_t, resid), xb, 0x07060302u);
}

// 8 packed u32 -> one 8xbf16 fragment (SELHI = hi halves, SELLO = residuals)
__device__ __forceinline__ uint4 mkfrag8(const uint32_t* p, uint32_t sel) {
  uint4 u;
  u.x = __builtin_amdgcn_perm(p[1], p[0], sel);
  u.y = __builtin_amdgcn_perm(p[3], p[2], sel);
  u.z = __builtin_amdgcn_perm(p[5], p[4], sel);
  u.w = __builtin_amdgcn_perm(p[7], p[6], sel);
  return u;
}

__device__ __forceinline__ f32x16 mf(uint4 a, uint4 b, f32x16 c) {
  return __builtin_amdgcn_mfma_f32_32x32x16_bf16(
      __builtin_bit_cast(bf16x8, a), __builtin_bit_cast(bf16x8, b), c, 0, 0, 0);
}

#define F4C(v, i) ((i) == 0 ? (v).x : (i) == 1 ? (v).y : (i) == 2 ? (v).z : (v).w)

// =====================================================================
// Kernel 1: fused projection GEMM (unchanged)
// =====================================================================
__global__ __launch_bounds__(256) void proj_gemm_kernel(
    const float* __restrict__ x,
    const float* __restrict__ Wk, const float* __restrict__ bk,
    const float* __restrict__ Wv, const float* __restrict__ bv,
    const float* __restrict__ Wq, const float* __restrict__ bq,
    float* __restrict__ proj)
{
  __shared__ float As[16][68];
  __shared__ float Bs[16][68];
  const int col0 = blockIdx.x * 64;
  const int row0 = blockIdx.y * 64;
  const float* Bp; const float* bias; int ldb, bcol, relu;
  if (col0 < 512)       { Bp = Wk; bias = bk; ldb = 512;  bcol = col0;        relu = 1; }
  else if (col0 < 1536) { Bp = Wv; bias = bv; ldb = 1024; bcol = col0 - 512;  relu = 0; }
  else                  { Bp = Wq; bias = bq; ldb = 512;  bcol = col0 - 1536; relu = 1; }
  const int tid = threadIdx.x;
  const int tr = tid >> 4, tc = tid & 15;
  float acc[4][4] = {};
  for (int k0 = 0; k0 < 1024; k0 += 16) {
    {
      int r = tid >> 2, kk = (tid & 3) << 2;
      float4 a4 = *(const float4*)&x[(size_t)(row0 + r) * 1024 + k0 + kk];
      As[kk+0][r] = a4.x; As[kk+1][r] = a4.y; As[kk+2][r] = a4.z; As[kk+3][r] = a4.w;
    }
    {
      int kr = tid >> 4, cc = (tid & 15) << 2;
      *(float4*)&Bs[kr][cc] = *(const float4*)&Bp[(size_t)(k0 + kr) * ldb + bcol + cc];
    }
    __syncthreads();
    #pragma unroll
    for (int k = 0; k < 16; ++k) {
      float4 av4 = *(const float4*)&As[k][tr*4];
      float4 bv4 = *(const float4*)&Bs[k][tc*4];
      float av[4] = {av4.x, av4.y, av4.z, av4.w};
      float bb[4] = {bv4.x, bv4.y, bv4.z, bv4.w};
      #pragma unroll
      for (int i = 0; i < 4; ++i)
        #pragma unroll
        for (int j = 0; j < 4; ++j)
          acc[i][j] = fmaf(av[i], bb[j], acc[i][j]);
    }
    __syncthreads();
  }
  #pragma unroll
  for (int i = 0; i < 4; ++i) {
    int r = row0 + tr*4 + i;
    #pragma unroll
    for (int j = 0; j < 4; ++j) {
      int cl = tc*4 + j;
      float v = acc[i][j] + bias[bcol + cl];
      if (relu) v = fmaxf(v, 0.f);
      proj[(size_t)r * 2048 + col0 + cl] = v;
    }
  }
}

// =====================================================================
// Kernel 2: fused memory kernel, R6.
//   vs R5: registers, not schedule, were the spill cause. Changes:
//   - pk tiles now FULL 32 rows/wave (LDS 50->80 KB, still 2 blocks/CU):
//     ELEM packs 4 values and writes b128 straight to LDS -> the 64-reg
//     oF/oN staging buffers are gone.
//   - phase C split into two 6-MFMA halves consumed immediately
//     (peak aC live 32 instead of 64).
//   - fq no longer copied to LDS; epilogue reads proj directly (L2-hot).
//   Keeps: pipelined phase-B chain (aBnext), memories prefetch (M_),
//   XOR-swizzled pk, no barriers in main loop.
// =====================================================================
__global__ __launch_bounds__(256, 2) void fused_mem_kernel(
    const float* __restrict__ memories,   // [512][2048][64]
    const float* __restrict__ addresses,  // [2048][64]
    const float* __restrict__ proj,       // [512][2048] = fk|v|fq
    float* __restrict__ attn)             // [512][512]
{
  // 80 KB arena:
  //  [0,2048)      fkFrag   (epilogue: n2stage/norm2/den2 overlay)
  //  [2048,4096)   vFrag
  //  [4096,20480)  pk region: 4 waves x { pF[32][64], pN[32][64] }
  //                (pbuf staging at start, stage[] in epilogue)
  __shared__ uint32_t SH[20480];

  const int b = blockIdx.x, tid = threadIdx.x;
  const int wave = tid >> 6, lane = tid & 63;
  const int g32 = lane >> 5, c32 = lane & 31;

  uint32_t* fkFrag = SH;
  uint32_t* vFrag  = SH + 2048;
  uint32_t* pkbase = SH + 4096;
  uint32_t* pF = pkbase + wave * 4096;   // [32][64] u32, col ^= (row&7)<<2
  uint32_t* pN = pF + 2048;

  // ---- stage proj row (pbuf overlays pk region) ----
  float* pbuf = (float*)pkbase;
  {
    const float* prow = proj + (size_t)b * 2048;
    *(float4*)&pbuf[tid*8]   = *(const float4*)&prow[tid*8];
    *(float4*)&pbuf[tid*8+4] = *(const float4*)&prow[tid*8+4];
  }
  __syncthreads();

  // ---- one-time fragment packing (wave w: kstep w, e-tile w) ----
  {
    const int ks = wave;
    float4 f0 = *(const float4*)&pbuf[c32*64 + ks*16 + g32*8];
    float4 f1 = *(const float4*)&pbuf[c32*64 + ks*16 + g32*8 + 4];
    uint32_t p[8] = { packsplit(f0.x), packsplit(f0.y), packsplit(f0.z), packsplit(f0.w),
                      packsplit(f1.x), packsplit(f1.y), packsplit(f1.z), packsplit(f1.w) };
    *(uint4*)&fkFrag[((ks*2+0)*64 + lane)*4] = mkfrag8(p, SELHI);
    *(uint4*)&fkFrag[((ks*2+1)*64 + lane)*4] = mkfrag8(p, SELLO);
    const int t = wave;
    uint32_t q[8];
    #pragma unroll
    for (int j = 0; j < 8; ++j) {
      int h = (g32*8 + j) & 7;
      q[j] = packsplit(pbuf[512 + h*128 + t*32 + c32]);
    }
    *(uint4*)&vFrag[((t*2+0)*64 + lane)*4] = mkfrag8(q, SELHI);
    *(uint4*)&vFrag[((t*2+1)*64 + lane)*4] = mkfrag8(q, SELLO);
  }
  __syncthreads();

  f32x16 Zv;
  #pragma unroll
  for (int r = 0; r < 16; ++r) Zv[r] = 0.f;
  f32x16 aD00 = Zv, aD01 = Zv, aD10 = Zv, aD11 = Zv;
  float n2a[32];
  #pragma unroll
  for (int k = 0; k < 32; ++k) n2a[k] = 0.f;

  const float* aRow0 = addresses + (size_t)(wave*512 + c32) * 64;
  const float* mRow0 = memories + ((size_t)b*2048 + wave*512 + c32) * 64;

  auto do_mfma = [&](int base) {
    uint32_t rf0[8], rf1[8], rn0[8], rn1[8];
    #pragma unroll
    for (int e = 0; e < 8; ++e) {
      const int row = base + g32*8 + e;
      const int cs = c32 ^ ((row & 7) << 2);
      rf0[e] = pF[row*64 + cs];
      rf1[e] = pF[row*64 + 32 + cs];
      rn0[e] = pN[row*64 + cs];
      rn1[e] = pN[row*64 + 32 + cs];
    }
    uint4 A0h = mkfrag8(rf0, SELHI), A0l = mkfrag8(rf0, SELLO);
    uint4 A1h = mkfrag8(rf1, SELHI), A1l = mkfrag8(rf1, SELLO);
    uint4 B0h = mkfrag8(rn0, SELHI), B0l = mkfrag8(rn0, SELLO);
    uint4 B1h = mkfrag8(rn1, SELHI), B1l = mkfrag8(rn1, SELLO);
    aD00 = mf(A0h,B0h,aD00); aD00 = mf(A0h,B0l,aD00); aD00 = mf(A0l,B0h,aD00);
    aD01 = mf(A0h,B1h,aD01); aD01 = mf(A0h,B1l,aD01); aD01 = mf(A0l,B1h,aD01);
    aD10 = mf(A1h,B0h,aD10); aD10 = mf(A1h,B0l,aD10); aD10 = mf(A1l,B0h,aD10);
    aD11 = mf(A1h,B1h,aD11); aD11 = mf(A1h,B1l,aD11); aD11 = mf(A1l,B1h,aD11);
  };

  // qa-pack + issue 12 B-MFMAs for superstep with address row AP into ACC
#define QAPACK_B(AP, ACC) do {                                         \
    _Pragma("unroll")                                                  \
    for (int ks = 0; ks < 4; ++ks) {                                   \
      float4 f0_ = *(const float4*)((AP) + ks*16 + g32*8);             \
      float4 f1_ = *(const float4*)((AP) + ks*16 + g32*8 + 4);         \
      uint32_t qp_[8] = {                                              \
        packsplit(fmaxf(f0_.x,0.f)), packsplit(fmaxf(f0_.y,0.f)),      \
        packsplit(fmaxf(f0_.z,0.f)), packsplit(fmaxf(f0_.w,0.f)),      \
        packsplit(fmaxf(f1_.x,0.f)), packsplit(fmaxf(f1_.y,0.f)),      \
        packsplit(fmaxf(f1_.z,0.f)), packsplit(fmaxf(f1_.w,0.f)) };    \
      uint4 Bh_ = mkfrag8(qp_, SELHI), Bl_ = mkfrag8(qp_, SELLO);      \
      uint4 Ah_ = *(uint4*)&fkFrag[((ks*2+0)*64 + lane)*4];            \
      uint4 Al_ = *(uint4*)&fkFrag[((ks*2+1)*64 + lane)*4];            \
      ACC = mf(Ah_,Bh_,ACC); ACC = mf(Ah_,Bl_,ACC); ACC = mf(Al_,Bh_,ACC); \
    } } while(0)

  // elementwise for one 32-col half; packs 4 values and writes b128
  // straight to the per-wave pk tile (row c32) -> no register staging.
#define ELEM(T2, ACU, ACW) do {                                        \
    const int sx_ = (c32 & 7) << 2;                                    \
    uint32_t* bF_ = &pF[c32*64];                                       \
    uint32_t* bN_ = &pN[c32*64];                                       \
    _Pragma("unroll")                                                  \
    for (int rq = 0; rq < 4; ++rq) {                                   \
      uint32_t pf_[4], pn_[4];                                         \
      _Pragma("unroll")                                                \
      for (int i = 0; i < 4; ++i) {                                    \
        const int r = rq*4 + i;                                        \
        float upd = ACU[r] * rden;                                     \
        float wx  = ACW[r] * rden;                                     \
        float wp  = 1.f / (1.f + __expf(-wx));                         \
        float mv  = F4C(M_[(T2)*4 + rq], i);                           \
        float av  = F4C(E_[rq & 1], i);                                \
        float nm  = fmaf(wp, upd - mv, mv);                            \
        float fv  = fmaxf(nm + av, 0.f);                               \
        n2a[(T2)*16 + r] += fv;                                        \
        pn_[i] = packsplit(nm);                                        \
        pf_[i] = packsplit(fv);                                        \
      }                                                                \
      if (rq == 1) { E_[0] = *(const float4*)(ap0 + (T2)*32 + 16 + g32*4);      \
                     E_[1] = *(const float4*)(ap0 + (T2)*32 + 16 + g32*4 + 8); }\
      const int col = (32*(T2) + 8*rq + 4*g32) ^ sx_;                  \
      *(uint4*)&bF_[col] = make_uint4(pf_[0],pf_[1],pf_[2],pf_[3]);    \
      *(uint4*)&bN_[col] = make_uint4(pn_[0],pn_[1],pn_[2],pn_[3]);    \
    } } while(0)

  // ---- prologue: B(0) + M(0) ----
  f32x16 aBcur = Zv, aBnext;
  float4 M_[8];
  QAPACK_B(aRow0, aBcur);
  #pragma unroll
  for (int k = 0; k < 8; ++k) M_[k] = *(const float4*)(mRow0 + k*8 + g32*4);

  #pragma unroll 1
  for (int ss = 0; ss < 16; ++ss) {
    asm volatile("" ::: "memory");  // block LICM of loop-invariant LDS reads

    // ---- 1. finish B(ss): S, den, rden, S-fragments ----
    float s0 = aBcur[0], s1 = aBcur[1], s2 = aBcur[2], s3 = aBcur[3];
    float own = (s0 + s1) + (s2 + s3);
    float den = own + __shfl_xor(own, 32) + EPSF;
    float rden = 1.f / den;
    float p0 = __shfl_xor(s0, 32), p1 = __shfl_xor(s1, 32),
          p2 = __shfl_xor(s2, 32), p3 = __shfl_xor(s3, 32);
    float z = (g32 == 0) ? 1.f : 0.f;
    uint32_t sp[8] = { packsplit(s0*z), packsplit(s1*z), packsplit(s2*z), packsplit(s3*z),
                       packsplit(p0*z), packsplit(p1*z), packsplit(p2*z), packsplit(p3*z) };
    uint4 Sh = mkfrag8(sp, SELHI), Sl = mkfrag8(sp, SELLO);

    // ---- 2. C-MFMAs, first half (e-tiles 0 and 2 -> update/write pair 0) ----
    f32x16 aC0 = Zv, aC2 = Zv;
    {
      uint4 Vh, Vl;
      Vh = *(uint4*)&vFrag[(0*64 + lane)*4]; Vl = *(uint4*)&vFrag[(1*64 + lane)*4];
      aC0 = mf(Vh, Sh, aC0); aC0 = mf(Vh, Sl, aC0); aC0 = mf(Vl, Sh, aC0);
      Vh = *(uint4*)&vFrag[(4*64 + lane)*4]; Vl = *(uint4*)&vFrag[(5*64 + lane)*4];
      aC2 = mf(Vh, Sh, aC2); aC2 = mf(Vh, Sl, aC2); aC2 = mf(Vl, Sh, aC2);
    }

    // ---- 3. pipeline: qa-pack + B-MFMAs for ss+1 (covers aC0/aC2 latency) ----
    aBnext = Zv;
    if (ss < 15) {
      const float* apn = aRow0 + (size_t)(ss+1) * 2048;
      QAPACK_B(apn, aBnext);
    }

    // ---- 4. ELEM half 0 (cols 0..31) ----
    const float* ap0 = aRow0 + (size_t)ss * 2048;
    float4 E_[2];
    E_[0] = *(const float4*)(ap0 + g32*4);
    E_[1] = *(const float4*)(ap0 + g32*4 + 8);
    ELEM(0, aC0, aC2);

    // ---- 5. C-MFMAs, second half (e-tiles 1 and 3) ----
    f32x16 aC1 = Zv, aC3 = Zv;
    {
      uint4 Vh, Vl;
      Vh = *(uint4*)&vFrag[(2*64 + lane)*4]; Vl = *(uint4*)&vFrag[(3*64 + lane)*4];
      aC1 = mf(Vh, Sh, aC1); aC1 = mf(Vh, Sl, aC1); aC1 = mf(Vl, Sh, aC1);
      Vh = *(uint4*)&vFrag[(6*64 + lane)*4]; Vl = *(uint4*)&vFrag[(7*64 + lane)*4];
      aC3 = mf(Vh, Sh, aC3); aC3 = mf(Vh, Sl, aC3); aC3 = mf(Vl, Sh, aC3);
    }

    // ---- 6. prefetch memories(ss+1) (covers aC1/aC3 latency too) ----
    if (ss < 15) {
      const float* mp = mRow0 + (size_t)(ss+1) * 2048;
      #pragma unroll
      for (int k = 0; k < 4; ++k) M_[k] = *(const float4*)(mp + k*8 + g32*4);
    }

    // ---- 7. ELEM half 1 (cols 32..63) ----
    E_[0] = *(const float4*)(ap0 + 32 + g32*4);
    E_[1] = *(const float4*)(ap0 + 32 + g32*4 + 8);
    ELEM(1, aC1, aC3);

    if (ss < 15) {
      const float* mp = mRow0 + (size_t)(ss+1) * 2048;
      #pragma unroll
      for (int k = 4; k < 8; ++k) M_[k] = *(const float4*)(mp + k*8 + g32*4);
    }

    // ---- 8. phase D: both 16-row chunks (pk fully written above) ----
    asm volatile("" ::: "memory");
    do_mfma(0);
    do_mfma(16);

    aBcur = aBnext;
  }

  // ================= epilogue =================
  __syncthreads();   // everyone done with fkFrag/vFrag/pk

  float* n2stageF = (float*)SH;            // [4][64]
  float* norm2F   = ((float*)SH) + 256;    // [64]
  float* den2F    = ((float*)SH) + 320;    // [8]
  float* stageF   = (float*)pkbase;        // [4][16][66]
  const float* fqg = proj + (size_t)b * 2048 + 1536;

  #pragma unroll
  for (int k = 0; k < 32; ++k) {
    float v = n2a[k];
    v += __shfl_xor(v, 1); v += __shfl_xor(v, 2); v += __shfl_xor(v, 4);
    v += __shfl_xor(v, 8); v += __shfl_xor(v, 16);
    n2a[k] = v;
  }
  if (c32 == 0) {
    #pragma unroll
    for (int t2 = 0; t2 < 2; ++t2)
      #pragma unroll
      for (int r = 0; r < 16; ++r) {
        const int j = 32*t2 + 8*(r>>2) + (r&3) + 4*g32;
        n2stageF[wave*64 + j] = n2a[t2*16 + r];
      }
  }
  __syncthreads();
  if (tid < 64)
    norm2F[tid] = (n2stageF[tid] + n2stageF[64+tid]) + (n2stageF[128+tid] + n2stageF[192+tid]);
  __syncthreads();
  if (tid < 8) {
    float s = 0.f;
    for (int d = 0; d < 64; ++d) s = fmaf(fqg[tid*64 + d], norm2F[d], s);
    den2F[tid] = s + EPSF;
  }

  const int hh = tid >> 5;
  const int ee = (tid & 31) * 2;
  float num2a = 0.f, num2b = 0.f;
  #pragma unroll
  for (int p = 0; p < 4; ++p) {
    const int ti = p >> 1, rh = p & 1;
    #pragma unroll
    for (int q = 0; q < 8; ++q) {
      const int rr = (q & 3) + 8*((q >> 2) & 1) + 4*g32;
      const int r = rh*8 + q;
      float v0 = (ti == 0) ? aD00[r] : aD10[r];
      float v1 = (ti == 0) ? aD01[r] : aD11[r];
      stageF[wave*1056 + rr*66 + c32]      = v0;
      stageF[wave*1056 + rr*66 + 32 + c32] = v1;
    }
    __syncthreads();
    #pragma unroll 8
    for (int dl = 0; dl < 16; ++dl) {
      float2 q0 = *(const float2*)&stageF[0*1056 + dl*66 + ee];
      float2 q1 = *(const float2*)&stageF[1*1056 + dl*66 + ee];
      float2 q2 = *(const float2*)&stageF[2*1056 + dl*66 + ee];
      float2 q3 = *(const float2*)&stageF[3*1056 + dl*66 + ee];
      float v0 = (q0.x + q1.x) + (q2.x + q3.x);
      float v1 = (q0.y + q1.y) + (q2.y + q3.y);
      float fv = fqg[hh*64 + p*16 + dl];
      num2a = fmaf(fv, v0, num2a);
      num2b = fmaf(fv, v1, num2b);
    }
    __syncthreads();
  }
  float rd2 = 1.f / den2F[hh];
  attn[(size_t)b*512 + hh*64 + ee]     = num2a * rd2;
  attn[(size_t)b*512 + hh*64 + ee + 1] = num2b * rd2;
#undef ELEM
#undef QAPACK_B
}

// =====================================================================
// Kernel 3: out = attn(512x512) @ Wm(512x1024) + bm (unchanged)
// =====================================================================
__global__ __launch_bounds__(256) void out_gemm_kernel(
    const float* __restrict__ A, const float* __restrict__ Wm,
    const float* __restrict__ bm, float* __restrict__ out)
{
  __shared__ float As[16][68];
  __shared__ float Bs[16][68];
  const int col0 = blockIdx.x * 64;
  const int row0 = blockIdx.y * 64;
  const int tid = threadIdx.x;
  const int tr = tid >> 4, tc = tid & 15;
  float acc[4][4] = {};
  for (int k0 = 0; k0 < 512; k0 += 16) {
    {
      int r = tid >> 2, kk = (tid & 3) << 2;
      float4 a4 = *(const float4*)&A[(size_t)(row0 + r) * 512 + k0 + kk];
      As[kk+0][r] = a4.x; As[kk+1][r] = a4.y; As[kk+2][r] = a4.z; As[kk+3][r] = a4.w;
    }
    {
      int kr = tid >> 4, cc = (tid & 15) << 2;
      *(float4*)&Bs[kr][cc] = *(const float4*)&Wm[(size_t)(k0 + kr) * 1024 + col0 + cc];
    }
    __syncthreads();
    #pragma unroll
    for (int k = 0; k < 16; ++k) {
      float4 av4 = *(const float4*)&As[k][tr*4];
      float4 bv4 = *(const float4*)&Bs[k][tc*4];
      float av[4] = {av4.x, av4.y, av4.z, av4.w};
      float bb[4] = {bv4.x, bv4.y, bv4.z, bv4.w};
      #pragma unroll
      for (int i = 0; i < 4; ++i)
        #pragma unroll
        for (int j = 0; j < 4; ++j)
          acc[i][j] = fmaf(av[i], bb[j], acc[i][j]);
    }
    __syncthreads();
  }
  #pragma unroll
  for (int i = 0; i < 4; ++i) {
    int r = row0 + tr*4 + i;
    #pragma unroll
    for (int j = 0; j < 4; ++j) {
      int c = col0 + tc*4 + j;
      out[(size_t)r * 1024 + c] = acc[i][j] + bm[c];
    }
  }
}

extern "C" void kernel_launch(void* const* d_in, const int* in_sizes, int n_in,
                              void* d_out, int out_size, void* d_ws, size_t ws_size,
                              hipStream_t stream)
{
  const float* x    = (const float*)d_in[0];
  const float* mem  = (const float*)d_in[1];
  const float* addr = (const float*)d_in[2];
  const float* Wk   = (const float*)d_in[3];
  const float* bk   = (const float*)d_in[4];
  const float* Wv   = (const float*)d_in[5];
  const float* bv   = (const float*)d_in[6];
  const float* Wq   = (const float*)d_in[7];
  const float* bq   = (const float*)d_in[8];
  const float* Wm   = (const float*)d_in[9];
  const float* bm   = (const float*)d_in[10];
  float* out  = (float*)d_out;
  float* ws   = (float*)d_ws;
  float* proj = ws;                        // 512*2048 floats (4 MB)
  float* attn = ws + (size_t)512 * 2048;   // 512*512 floats (1 MB)

  hipLaunchKernelGGL(proj_gemm_kernel, dim3(32, 8), dim3(256), 0, stream,
                     x, Wk, bk, Wv, bv, Wq, bq, proj);
  hipLaunchKernelGGL(fused_mem_kernel, dim3(512), dim3(256), 0, stream,
                     mem, addr, proj, attn);
  hipLaunchKernelGGL(out_gemm_kernel, dim3(16, 8), dim3(256), 0, stream,
                     attn, Wm, bm, out);
}

// Round 8
// 231.180 us; speedup vs baseline: 3.5099x; 1.0179x over previous
//
#include <hip/hip_runtime.h>
#include <hip/hip_bf16.h>
#include <math.h>

#define EPSF 1e-5f
#define SELHI 0x05040100u
#define SELLO 0x07060302u

typedef __attribute__((ext_vector_type(8))) short bf16x8;
typedef __attribute__((ext_vector_type(16))) float f32x16;

// pack float -> u32 { low16 = hi-bf16 (truncated), high16 = lo-bf16 (residual) }
__device__ __forceinline__ uint32_t packsplit(float x) {
  uint32_t xb = __builtin_bit_cast(uint32_t, x);
  float hi = __builtin_bit_cast(float, xb & 0xFFFF0000u);
  float resid = x - hi;
  return __builtin_amdgcn_perm(__builtin_bit_cast(uint32_t, resid), xb, 0x07060302u);
}

// 8 packed u32 -> one 8xbf16 fragment (SELHI = hi halves, SELLO = residuals)
__device__ __forceinline__ uint4 mkfrag8(const uint32_t* p, uint32_t sel) {
  uint4 u;
  u.x = __builtin_amdgcn_perm(p[1], p[0], sel);
  u.y = __builtin_amdgcn_perm(p[3], p[2], sel);
  u.z = __builtin_amdgcn_perm(p[5], p[4], sel);
  u.w = __builtin_amdgcn_perm(p[7], p[6], sel);
  return u;
}

__device__ __forceinline__ f32x16 mf(uint4 a, uint4 b, f32x16 c) {
  return __builtin_amdgcn_mfma_f32_32x32x16_bf16(
      __builtin_bit_cast(bf16x8, a), __builtin_bit_cast(bf16x8, b), c, 0, 0, 0);
}

#define F4C(v, i) ((i) == 0 ? (v).x : (i) == 1 ? (v).y : (i) == 2 ? (v).z : (v).w)

// =====================================================================
// Kernel 1: fused projection GEMM (unchanged)
// =====================================================================
__global__ __launch_bounds__(256) void proj_gemm_kernel(
    const float* __restrict__ x,
    const float* __restrict__ Wk, const float* __restrict__ bk,
    const float* __restrict__ Wv, const float* __restrict__ bv,
    const float* __restrict__ Wq, const float* __restrict__ bq,
    float* __restrict__ proj)
{
  __shared__ float As[16][68];
  __shared__ float Bs[16][68];
  const int col0 = blockIdx.x * 64;
  const int row0 = blockIdx.y * 64;
  const float* Bp; const float* bias; int ldb, bcol, relu;
  if (col0 < 512)       { Bp = Wk; bias = bk; ldb = 512;  bcol = col0;        relu = 1; }
  else if (col0 < 1536) { Bp = Wv; bias = bv; ldb = 1024; bcol = col0 - 512;  relu = 0; }
  else                  { Bp = Wq; bias = bq; ldb = 512;  bcol = col0 - 1536; relu = 1; }
  const int tid = threadIdx.x;
  const int tr = tid >> 4, tc = tid & 15;
  float acc[4][4] = {};
  for (int k0 = 0; k0 < 1024; k0 += 16) {
    {
      int r = tid >> 2, kk = (tid & 3) << 2;
      float4 a4 = *(const float4*)&x[(size_t)(row0 + r) * 1024 + k0 + kk];
      As[kk+0][r] = a4.x; As[kk+1][r] = a4.y; As[kk+2][r] = a4.z; As[kk+3][r] = a4.w;
    }
    {
      int kr = tid >> 4, cc = (tid & 15) << 2;
      *(float4*)&Bs[kr][cc] = *(const float4*)&Bp[(size_t)(k0 + kr) * ldb + bcol + cc];
    }
    __syncthreads();
    #pragma unroll
    for (int k = 0; k < 16; ++k) {
      float4 av4 = *(const float4*)&As[k][tr*4];
      float4 bv4 = *(const float4*)&Bs[k][tc*4];
      float av[4] = {av4.x, av4.y, av4.z, av4.w};
      float bb[4] = {bv4.x, bv4.y, bv4.z, bv4.w};
      #pragma unroll
      for (int i = 0; i < 4; ++i)
        #pragma unroll
        for (int j = 0; j < 4; ++j)
          acc[i][j] = fmaf(av[i], bb[j], acc[i][j]);
    }
    __syncthreads();
  }
  #pragma unroll
  for (int i = 0; i < 4; ++i) {
    int r = row0 + tr*4 + i;
    #pragma unroll
    for (int j = 0; j < 4; ++j) {
      int cl = tc*4 + j;
      float v = acc[i][j] + bias[bcol + cl];
      if (relu) v = fmaxf(v, 0.f);
      proj[(size_t)r * 2048 + col0 + cl] = v;
    }
  }
}

// =====================================================================
// Kernel 2: fused memory kernel, R7.
//   vs R6 (vmcnt in-order-drain fix): within a superstep, ALL fast
//   L1/L2 loads (addresses rows) are issued BEFORE any HBM memories
//   prefetch, so no later wait drains the M_ stream early. M_ loads
//   now stay in flight for ~a full superstep (first draining wait is
//   next superstep's QAPACK). Also: rden folded into the S-fragment
//   pack (8 muls replace 64 ELEM muls).
// =====================================================================
__global__ __launch_bounds__(256, 2) void fused_mem_kernel(
    const float* __restrict__ memories,   // [512][2048][64]
    const float* __restrict__ addresses,  // [2048][64]
    const float* __restrict__ proj,       // [512][2048] = fk|v|fq
    float* __restrict__ attn)             // [512][512]
{
  // 80 KB arena:
  //  [0,2048)      fkFrag   (epilogue: n2stage/norm2/den2 overlay)
  //  [2048,4096)   vFrag
  //  [4096,20480)  pk region: 4 waves x { pF[32][64], pN[32][64] }
  __shared__ uint32_t SH[20480];

  const int b = blockIdx.x, tid = threadIdx.x;
  const int wave = tid >> 6, lane = tid & 63;
  const int g32 = lane >> 5, c32 = lane & 31;

  uint32_t* fkFrag = SH;
  uint32_t* vFrag  = SH + 2048;
  uint32_t* pkbase = SH + 4096;
  uint32_t* pF = pkbase + wave * 4096;   // [32][64] u32, col ^= (row&7)<<2
  uint32_t* pN = pF + 2048;

  // ---- stage proj row (pbuf overlays pk region) ----
  float* pbuf = (float*)pkbase;
  {
    const float* prow = proj + (size_t)b * 2048;
    *(float4*)&pbuf[tid*8]   = *(const float4*)&prow[tid*8];
    *(float4*)&pbuf[tid*8+4] = *(const float4*)&prow[tid*8+4];
  }
  __syncthreads();

  // ---- one-time fragment packing (wave w: kstep w, e-tile w) ----
  {
    const int ks = wave;
    float4 f0 = *(const float4*)&pbuf[c32*64 + ks*16 + g32*8];
    float4 f1 = *(const float4*)&pbuf[c32*64 + ks*16 + g32*8 + 4];
    uint32_t p[8] = { packsplit(f0.x), packsplit(f0.y), packsplit(f0.z), packsplit(f0.w),
                      packsplit(f1.x), packsplit(f1.y), packsplit(f1.z), packsplit(f1.w) };
    *(uint4*)&fkFrag[((ks*2+0)*64 + lane)*4] = mkfrag8(p, SELHI);
    *(uint4*)&fkFrag[((ks*2+1)*64 + lane)*4] = mkfrag8(p, SELLO);
    const int t = wave;
    uint32_t q[8];
    #pragma unroll
    for (int j = 0; j < 8; ++j) {
      int h = (g32*8 + j) & 7;
      q[j] = packsplit(pbuf[512 + h*128 + t*32 + c32]);
    }
    *(uint4*)&vFrag[((t*2+0)*64 + lane)*4] = mkfrag8(q, SELHI);
    *(uint4*)&vFrag[((t*2+1)*64 + lane)*4] = mkfrag8(q, SELLO);
  }
  __syncthreads();

  f32x16 Zv;
  #pragma unroll
  for (int r = 0; r < 16; ++r) Zv[r] = 0.f;
  f32x16 aD00 = Zv, aD01 = Zv, aD10 = Zv, aD11 = Zv;
  float n2a[32];
  #pragma unroll
  for (int k = 0; k < 32; ++k) n2a[k] = 0.f;

  const float* aRow0 = addresses + (size_t)(wave*512 + c32) * 64;
  const float* mRow0 = memories + ((size_t)b*2048 + wave*512 + c32) * 64;

  auto do_mfma = [&](int base) {
    uint32_t rf0[8], rf1[8], rn0[8], rn1[8];
    #pragma unroll
    for (int e = 0; e < 8; ++e) {
      const int row = base + g32*8 + e;
      const int cs = c32 ^ ((row & 7) << 2);
      rf0[e] = pF[row*64 + cs];
      rf1[e] = pF[row*64 + 32 + cs];
      rn0[e] = pN[row*64 + cs];
      rn1[e] = pN[row*64 + 32 + cs];
    }
    uint4 A0h = mkfrag8(rf0, SELHI), A0l = mkfrag8(rf0, SELLO);
    uint4 A1h = mkfrag8(rf1, SELHI), A1l = mkfrag8(rf1, SELLO);
    uint4 B0h = mkfrag8(rn0, SELHI), B0l = mkfrag8(rn0, SELLO);
    uint4 B1h = mkfrag8(rn1, SELHI), B1l = mkfrag8(rn1, SELLO);
    aD00 = mf(A0h,B0h,aD00); aD00 = mf(A0h,B0l,aD00); aD00 = mf(A0l,B0h,aD00);
    aD01 = mf(A0h,B1h,aD01); aD01 = mf(A0h,B1l,aD01); aD01 = mf(A0l,B1h,aD01);
    aD10 = mf(A1h,B0h,aD10); aD10 = mf(A1h,B0l,aD10); aD10 = mf(A1l,B0h,aD10);
    aD11 = mf(A1h,B1h,aD11); aD11 = mf(A1h,B1l,aD11); aD11 = mf(A1l,B1h,aD11);
  };

  // qa-pack + issue 12 B-MFMAs for superstep with address row AP into ACC
#define QAPACK_B(AP, ACC) do {                                         \
    _Pragma("unroll")                                                  \
    for (int ks = 0; ks < 4; ++ks) {                                   \
      float4 f0_ = *(const float4*)((AP) + ks*16 + g32*8);             \
      float4 f1_ = *(const float4*)((AP) + ks*16 + g32*8 + 4);         \
      uint32_t qp_[8] = {                                              \
        packsplit(fmaxf(f0_.x,0.f)), packsplit(fmaxf(f0_.y,0.f)),      \
        packsplit(fmaxf(f0_.z,0.f)), packsplit(fmaxf(f0_.w,0.f)),      \
        packsplit(fmaxf(f1_.x,0.f)), packsplit(fmaxf(f1_.y,0.f)),      \
        packsplit(fmaxf(f1_.z,0.f)), packsplit(fmaxf(f1_.w,0.f)) };    \
      uint4 Bh_ = mkfrag8(qp_, SELHI), Bl_ = mkfrag8(qp_, SELLO);      \
      uint4 Ah_ = *(uint4*)&fkFrag[((ks*2+0)*64 + lane)*4];            \
      uint4 Al_ = *(uint4*)&fkFrag[((ks*2+1)*64 + lane)*4];            \
      ACC = mf(Ah_,Bh_,ACC); ACC = mf(Ah_,Bl_,ACC); ACC = mf(Al_,Bh_,ACC); \
    } } while(0)

  // elementwise for one 32-col half. aC already carries num*rden (rden
  // folded into S pack), so no per-element muls. Packs 4 values and
  // writes b128 straight to the per-wave pk tile (row c32).
#define ELEM(T2, ACU, ACW, EARR)                                       \
    { const int sx_ = (c32 & 7) << 2;                                  \
      uint32_t* bF_ = &pF[c32*64];                                     \
      uint32_t* bN_ = &pN[c32*64];                                     \
      _Pragma("unroll")                                                \
      for (int rq = 0; rq < 4; ++rq) {                                 \
        uint32_t pf_[4], pn_[4];                                       \
        _Pragma("unroll")                                              \
        for (int i = 0; i < 4; ++i) {                                  \
          const int r = rq*4 + i;                                      \
          float upd = ACU[r];                                          \
          float wx  = ACW[r];                                          \
          float wp  = 1.f / (1.f + __expf(-wx));                       \
          float mv  = F4C(M_[(T2)*4 + rq], i);                         \
          float av  = F4C(EARR[rq], i);                                \
          float nm  = fmaf(wp, upd - mv, mv);                          \
          float fv  = fmaxf(nm + av, 0.f);                             \
          n2a[(T2)*16 + r] += fv;                                      \
          pn_[i] = packsplit(nm);                                      \
          pf_[i] = packsplit(fv);                                      \
        }                                                              \
        const int col = (32*(T2) + 8*rq + 4*g32) ^ sx_;                \
        *(uint4*)&bF_[col] = make_uint4(pf_[0],pf_[1],pf_[2],pf_[3]);  \
        *(uint4*)&bN_[col] = make_uint4(pn_[0],pn_[1],pn_[2],pn_[3]);  \
      } }

  // ---- prologue: B(0) + M(0) ----
  f32x16 aBcur = Zv, aBnext;
  float4 M_[8];
  QAPACK_B(aRow0, aBcur);
  #pragma unroll
  for (int k = 0; k < 8; ++k) M_[k] = *(const float4*)(mRow0 + k*8 + g32*4);

  #pragma unroll 1
  for (int ss = 0; ss < 16; ++ss) {
    asm volatile("" ::: "memory");  // block LICM of loop-invariant LDS reads

    // ---- 1. finish B(ss): S, den, rden folded into S-fragment ----
    float s0 = aBcur[0], s1 = aBcur[1], s2 = aBcur[2], s3 = aBcur[3];
    float own = (s0 + s1) + (s2 + s3);
    float den = own + __shfl_xor(own, 32) + EPSF;
    float rden = 1.f / den;
    float p0 = __shfl_xor(s0, 32), p1 = __shfl_xor(s1, 32),
          p2 = __shfl_xor(s2, 32), p3 = __shfl_xor(s3, 32);
    float rm = (g32 == 0) ? rden : 0.f;   // K-pad mask * rden
    uint32_t sp[8] = { packsplit(s0*rm), packsplit(s1*rm), packsplit(s2*rm), packsplit(s3*rm),
                       packsplit(p0*rm), packsplit(p1*rm), packsplit(p2*rm), packsplit(p3*rm) };
    uint4 Sh = mkfrag8(sp, SELHI), Sl = mkfrag8(sp, SELLO);

    // ---- 2. C-MFMAs, first half (e-tiles 0 and 2) ----
    f32x16 aC0 = Zv, aC2 = Zv;
    {
      uint4 Vh, Vl;
      Vh = *(uint4*)&vFrag[(0*64 + lane)*4]; Vl = *(uint4*)&vFrag[(1*64 + lane)*4];
      aC0 = mf(Vh, Sh, aC0); aC0 = mf(Vh, Sl, aC0); aC0 = mf(Vl, Sh, aC0);
      Vh = *(uint4*)&vFrag[(4*64 + lane)*4]; Vl = *(uint4*)&vFrag[(5*64 + lane)*4];
      aC2 = mf(Vh, Sh, aC2); aC2 = mf(Vh, Sl, aC2); aC2 = mf(Vl, Sh, aC2);
    }

    // ---- 3. pipeline: qa-pack + B-MFMAs for ss+1 (L2-fast loads) ----
    aBnext = Zv;
    if (ss < 15) {
      const float* apn = aRow0 + (size_t)(ss+1) * 2048;
      QAPACK_B(apn, aBnext);
    }

    // ---- 4. ALL addresses loads for ELEM (L1-hot), BEFORE any M_ issue ----
    const float* ap0 = aRow0 + (size_t)ss * 2048;
    float4 E0_[4], E1_[4];
    #pragma unroll
    for (int rq = 0; rq < 4; ++rq) E0_[rq] = *(const float4*)(ap0 + 8*rq + g32*4);
    #pragma unroll
    for (int rq = 0; rq < 4; ++rq) E1_[rq] = *(const float4*)(ap0 + 32 + 8*rq + g32*4);

    // ---- 5. ELEM half 0 (consumes old M_[0..3]; waits only fast loads) ----
    ELEM(0, aC0, aC2, E0_);

    // ---- 6. M_[0..3] <- ss+1 (HBM; stays in flight past this superstep) ----
    if (ss < 15) {
      const float* mp = mRow0 + (size_t)(ss+1) * 2048;
      #pragma unroll
      for (int k = 0; k < 4; ++k) M_[k] = *(const float4*)(mp + k*8 + g32*4);
    }

    // ---- 7. C-MFMAs, second half (e-tiles 1 and 3) ----
    f32x16 aC1 = Zv, aC3 = Zv;
    {
      uint4 Vh, Vl;
      Vh = *(uint4*)&vFrag[(2*64 + lane)*4]; Vl = *(uint4*)&vFrag[(3*64 + lane)*4];
      aC1 = mf(Vh, Sh, aC1); aC1 = mf(Vh, Sl, aC1); aC1 = mf(Vl, Sh, aC1);
      Vh = *(uint4*)&vFrag[(6*64 + lane)*4]; Vl = *(uint4*)&vFrag[(7*64 + lane)*4];
      aC3 = mf(Vh, Sh, aC3); aC3 = mf(Vh, Sl, aC3); aC3 = mf(Vl, Sh, aC3);
    }

    // ---- 8. ELEM half 1 (E1_ preloaded before M_ -> no M_ drain) ----
    ELEM(1, aC1, aC3, E1_);

    // ---- 9. M_[4..7] <- ss+1 ----
    if (ss < 15) {
      const float* mp = mRow0 + (size_t)(ss+1) * 2048;
      #pragma unroll
      for (int k = 4; k < 8; ++k) M_[k] = *(const float4*)(mp + k*8 + g32*4);
    }

    // ---- 10. phase D: both 16-row chunks (DS + MFMA only, no vmem) ----
    asm volatile("" ::: "memory");
    do_mfma(0);
    do_mfma(16);

    aBcur = aBnext;
  }

  // ================= epilogue =================
  __syncthreads();   // everyone done with fkFrag/vFrag/pk

  float* n2stageF = (float*)SH;            // [4][64]
  float* norm2F   = ((float*)SH) + 256;    // [64]
  float* den2F    = ((float*)SH) + 320;    // [8]
  float* stageF   = (float*)pkbase;        // [4][16][66]
  const float* fqg = proj + (size_t)b * 2048 + 1536;

  #pragma unroll
  for (int k = 0; k < 32; ++k) {
    float v = n2a[k];
    v += __shfl_xor(v, 1); v += __shfl_xor(v, 2); v += __shfl_xor(v, 4);
    v += __shfl_xor(v, 8); v += __shfl_xor(v, 16);
    n2a[k] = v;
  }
  if (c32 == 0) {
    #pragma unroll
    for (int t2 = 0; t2 < 2; ++t2)
      #pragma unroll
      for (int r = 0; r < 16; ++r) {
        const int j = 32*t2 + 8*(r>>2) + (r&3) + 4*g32;
        n2stageF[wave*64 + j] = n2a[t2*16 + r];
      }
  }
  __syncthreads();
  if (tid < 64)
    norm2F[tid] = (n2stageF[tid] + n2stageF[64+tid]) + (n2stageF[128+tid] + n2stageF[192+tid]);
  __syncthreads();
  if (tid < 8) {
    float s = 0.f;
    for (int d = 0; d < 64; ++d) s = fmaf(fqg[tid*64 + d], norm2F[d], s);
    den2F[tid] = s + EPSF;
  }

  const int hh = tid >> 5;
  const int ee = (tid & 31) * 2;
  float num2a = 0.f, num2b = 0.f;
  #pragma unroll
  for (int p = 0; p < 4; ++p) {
    const int ti = p >> 1, rh = p & 1;
    #pragma unroll
    for (int q = 0; q < 8; ++q) {
      const int rr = (q & 3) + 8*((q >> 2) & 1) + 4*g32;
      const int r = rh*8 + q;
      float v0 = (ti == 0) ? aD00[r] : aD10[r];
      float v1 = (ti == 0) ? aD01[r] : aD11[r];
      stageF[wave*1056 + rr*66 + c32]      = v0;
      stageF[wave*1056 + rr*66 + 32 + c32] = v1;
    }
    __syncthreads();
    #pragma unroll 8
    for (int dl = 0; dl < 16; ++dl) {
      float2 q0 = *(const float2*)&stageF[0*1056 + dl*66 + ee];
      float2 q1 = *(const float2*)&stageF[1*1056 + dl*66 + ee];
      float2 q2 = *(const float2*)&stageF[2*1056 + dl*66 + ee];
      float2 q3 = *(const float2*)&stageF[3*1056 + dl*66 + ee];
      float v0 = (q0.x + q1.x) + (q2.x + q3.x);
      float v1 = (q0.y + q1.y) + (q2.y + q3.y);
      float fv = fqg[hh*64 + p*16 + dl];
      num2a = fmaf(fv, v0, num2a);
      num2b = fmaf(fv, v1, num2b);
    }
    __syncthreads();
  }
  float rd2 = 1.f / den2F[hh];
  attn[(size_t)b*512 + hh*64 + ee]     = num2a * rd2;
  attn[(size_t)b*512 + hh*64 + ee + 1] = num2b * rd2;
#undef ELEM
#undef QAPACK_B
}

// =====================================================================
// Kernel 3: out = attn(512x512) @ Wm(512x1024) + bm (unchanged)
// =====================================================================
__global__ __launch_bounds__(256) void out_gemm_kernel(
    const float* __restrict__ A, const float* __restrict__ Wm,
    const float* __restrict__ bm, float* __restrict__ out)
{
  __shared__ float As[16][68];
  __shared__ float Bs[16][68];
  const int col0 = blockIdx.x * 64;
  const int row0 = blockIdx.y * 64;
  const int tid = threadIdx.x;
  const int tr = tid >> 4, tc = tid & 15;
  float acc[4][4] = {};
  for (int k0 = 0; k0 < 512; k0 += 16) {
    {
      int r = tid >> 2, kk = (tid & 3) << 2;
      float4 a4 = *(const float4*)&A[(size_t)(row0 + r) * 512 + k0 + kk];
      As[kk+0][r] = a4.x; As[kk+1][r] = a4.y; As[kk+2][r] = a4.z; As[kk+3][r] = a4.w;
    }
    {
      int kr = tid >> 4, cc = (tid & 15) << 2;
      *(float4*)&Bs[kr][cc] = *(const float4*)&Wm[(size_t)(k0 + kr) * 1024 + col0 + cc];
    }
    __syncthreads();
    #pragma unroll
    for (int k = 0; k < 16; ++k) {
      float4 av4 = *(const float4*)&As[k][tr*4];
      float4 bv4 = *(const float4*)&Bs[k][tc*4];
      float av[4] = {av4.x, av4.y, av4.z, av4.w};
      float bb[4] = {bv4.x, bv4.y, bv4.z, bv4.w};
      #pragma unroll
      for (int i = 0; i < 4; ++i)
        #pragma unroll
        for (int j = 0; j < 4; ++j)
          acc[i][j] = fmaf(av[i], bb[j], acc[i][j]);
    }
    __syncthreads();
  }
  #pragma unroll
  for (int i = 0; i < 4; ++i) {
    int r = row0 + tr*4 + i;
    #pragma unroll
    for (int j = 0; j < 4; ++j) {
      int c = col0 + tc*4 + j;
      out[(size_t)r * 1024 + c] = acc[i][j] + bm[c];
    }
  }
}

extern "C" void kernel_launch(void* const* d_in, const int* in_sizes, int n_in,
                              void* d_out, int out_size, void* d_ws, size_t ws_size,
                              hipStream_t stream)
{
  const float* x    = (const float*)d_in[0];
  const float* mem  = (const float*)d_in[1];
  const float* addr = (const float*)d_in[2];
  const float* Wk   = (const float*)d_in[3];
  const float* bk   = (const float*)d_in[4];
  const float* Wv   = (const float*)d_in[5];
  const float* bv   = (const float*)d_in[6];
  const float* Wq   = (const float*)d_in[7];
  const float* bq   = (const float*)d_in[8];
  const float* Wm   = (const float*)d_in[9];
  const float* bm   = (const float*)d_in[10];
  float* out  = (float*)d_out;
  float* ws   = (float*)d_ws;
  float* proj = ws;                        // 512*2048 floats (4 MB)
  float* attn = ws + (size_t)512 * 2048;   // 512*512 floats (1 MB)

  hipLaunchKernelGGL(proj_gemm_kernel, dim3(32, 8), dim3(256), 0, stream,
                     x, Wk, bk, Wv, bv, Wq, bq, proj);
  hipLaunchKernelGGL(fused_mem_kernel, dim3(512), dim3(256), 0, stream,
                     mem, addr, proj, attn);
  hipLaunchKernelGGL(out_gemm_kernel, dim3(16, 8), dim3(256), 0, stream,
                     attn, Wm, bm, out);
}